// Round 1
// baseline (4094.487 us; speedup 1.0000x reference)
//
#include <hip/hip_runtime.h>

// H2GCNConv: out[:, 0:128]   = segment_sum(w1 * x[col1], row1)
//            out[:, 128:256] = segment_sum(w2 * x[col2], row2)
// N = 50000, d = 128, out stride = 256 floats.
//
// Round 0: correctness-first atomic scatter. 32 lanes per edge, float4 per
// lane (128 floats = 32 lanes x 4). Atomics are device-scope by default on
// gfx950 (cross-XCD safe).

#define OUT_STRIDE 256
#define D 128

__global__ void spmm_scatter(const float* __restrict__ x,
                             const int* __restrict__ ei,   // [2, E]: rows then cols
                             const float* __restrict__ w,
                             float* __restrict__ out,
                             int E, int col_off) {
    long long gid = (long long)blockIdx.x * blockDim.x + threadIdx.x;
    int e    = (int)(gid >> 5);   // 32 threads per edge
    int lane = (int)(gid & 31);
    if (e >= E) return;

    int row   = ei[e];
    int col   = ei[E + e];
    float wv  = w[e];

    const float4* xv = (const float4*)(x + (size_t)col * D);
    float4 v = xv[lane];

    float* o = out + (size_t)row * OUT_STRIDE + col_off + lane * 4;
    atomicAdd(o + 0, wv * v.x);
    atomicAdd(o + 1, wv * v.y);
    atomicAdd(o + 2, wv * v.z);
    atomicAdd(o + 3, wv * v.w);
}

extern "C" void kernel_launch(void* const* d_in, const int* in_sizes, int n_in,
                              void* d_out, int out_size, void* d_ws, size_t ws_size,
                              hipStream_t stream) {
    const float* x   = (const float*)d_in[0];
    const int*   ei1 = (const int*)d_in[1];
    const float* w1  = (const float*)d_in[2];
    const int*   ei2 = (const int*)d_in[3];
    const float* w2  = (const float*)d_in[4];
    float* out = (float*)d_out;

    const int E1 = in_sizes[1] / 2;   // 800000
    const int E2 = in_sizes[3] / 2;   // 1600000

    // Harness re-poisons d_out with 0xAA before every launch: zero it.
    hipMemsetAsync(d_out, 0, (size_t)out_size * sizeof(float), stream);

    const int block = 256;
    {
        long long threads = (long long)E1 * 32;
        int grid = (int)((threads + block - 1) / block);
        spmm_scatter<<<grid, block, 0, stream>>>(x, ei1, w1, out, E1, 0);
    }
    {
        long long threads = (long long)E2 * 32;
        int grid = (int)((threads + block - 1) / block);
        spmm_scatter<<<grid, block, 0, stream>>>(x, ei2, w2, out, E2, D);
    }
}

// Round 2
// 632.233 us; speedup vs baseline: 6.4762x; 6.4762x over previous
//
#include <hip/hip_runtime.h>

// H2GCNConv: out[:, 0:128]   = segment_sum(w1 * x[col1], row1)
//            out[:, 128:256] = segment_sum(w2 * x[col2], row2)
// N = 50000, d = 128, out stride = 256 floats.
//
// Round 2: on-device CSR build + gather SpMM (no atomics on the fat path).
// Round 0 atomic-scatter measured 3.2 GB WRITE_SIZE (atomic RMW amplification);
// CSR path writes output exactly once (51 MB) and gathers x from L2/L3.

#define N_NODES 50000
#define D 128
#define OUT_STRIDE 256

static inline size_t align256(size_t x) { return (x + 255) & ~(size_t)255; }

// ---------------- CSR build ----------------

__global__ void hist_kernel(const int* __restrict__ ei1, int E1,
                            const int* __restrict__ ei2, int E2,
                            int* cnt1, int* cnt2) {
    int t = blockIdx.x * blockDim.x + threadIdx.x;
    if (t < E1) {
        atomicAdd(&cnt1[ei1[t]], 1);
    } else {
        int u = t - E1;
        if (u < E2) atomicAdd(&cnt2[ei2[u]], 1);
    }
}

// Exclusive scan of cnt -> off. grid=2 (block 0: graph1, block 1: graph2),
// 1024 threads = 16 waves; shuffle scan per wave + LDS combine, running carry.
__global__ void scan_kernel(const int* cnt1, int* off1,
                            const int* cnt2, int* off2, int n) {
    const int* cnt = blockIdx.x ? cnt2 : cnt1;
    int* off       = blockIdx.x ? off2 : off1;
    __shared__ int wsum[16];
    __shared__ int wpre[17];
    __shared__ int carry;
    int lane = threadIdx.x & 63;
    int wid  = threadIdx.x >> 6;
    if (threadIdx.x == 0) carry = 0;
    __syncthreads();
    for (int base = 0; base < n; base += 1024) {
        int i = base + (int)threadIdx.x;
        int v = (i < n) ? cnt[i] : 0;
        int sum = v;  // inclusive scan within wave
        #pragma unroll
        for (int s = 1; s < 64; s <<= 1) {
            int t = __shfl_up(sum, s, 64);
            if (lane >= s) sum += t;
        }
        if (lane == 63) wsum[wid] = sum;
        __syncthreads();
        if (threadIdx.x == 0) {
            int a = 0;
            #pragma unroll
            for (int k = 0; k < 16; ++k) { wpre[k] = a; a += wsum[k]; }
            wpre[16] = a;
        }
        __syncthreads();
        if (i < n) off[i] = carry + wpre[wid] + sum - v;  // exclusive
        __syncthreads();
        if (threadIdx.x == 0) carry += wpre[16];
        __syncthreads();
    }
}

// Scatter edges into row buckets. atomicAdd on off[] itself: afterwards
// off[r] = end of row r (= start of row r+1); start of row r is off[r-1].
__global__ void scatter_kernel(const int* __restrict__ ei,
                               const float* __restrict__ w, int E,
                               int* off, int2* colw) {
    int t = blockIdx.x * blockDim.x + threadIdx.x;
    if (t >= E) return;
    int row = ei[t];
    int pos = atomicAdd(&off[row], 1);
    colw[pos] = make_int2(ei[E + t], __float_as_int(w[t]));
}

// ---------------- SpMM: one wave per row, both graphs ----------------

__global__ void __launch_bounds__(256) spmm_csr(const float* __restrict__ x,
                                                const int* __restrict__ off1,
                                                const int2* __restrict__ colw1,
                                                const int* __restrict__ off2,
                                                const int2* __restrict__ colw2,
                                                float* __restrict__ out) {
    int row  = (int)((blockIdx.x * blockDim.x + threadIdx.x) >> 6);
    int lane = threadIdx.x & 63;
    if (row >= N_NODES) return;
    float2* o = (float2*)(out + (size_t)row * OUT_STRIDE);
    {
        int s = row ? off1[row - 1] : 0;
        int e = off1[row];
        float2 acc = make_float2(0.f, 0.f);
        for (int j = s; j < e; ++j) {
            int2 cw = colw1[j];                       // broadcast load
            float wv = __int_as_float(cw.y);
            float2 v = ((const float2*)(x + (size_t)cw.x * D))[lane];
            acc.x += wv * v.x;
            acc.y += wv * v.y;
        }
        o[lane] = acc;
    }
    {
        int s = row ? off2[row - 1] : 0;
        int e = off2[row];
        float2 acc = make_float2(0.f, 0.f);
        for (int j = s; j < e; ++j) {
            int2 cw = colw2[j];
            float wv = __int_as_float(cw.y);
            float2 v = ((const float2*)(x + (size_t)cw.x * D))[lane];
            acc.x += wv * v.x;
            acc.y += wv * v.y;
        }
        o[64 + lane] = acc;
    }
}

// ---------------- Round-0 fallback (if ws too small) ----------------

__global__ void spmm_scatter(const float* __restrict__ x,
                             const int* __restrict__ ei,
                             const float* __restrict__ w,
                             float* __restrict__ out,
                             int E, int col_off) {
    long long gid = (long long)blockIdx.x * blockDim.x + threadIdx.x;
    int e    = (int)(gid >> 5);
    int lane = (int)(gid & 31);
    if (e >= E) return;
    int row  = ei[e];
    int col  = ei[E + e];
    float wv = w[e];
    const float4* xv = (const float4*)(x + (size_t)col * D);
    float4 v = xv[lane];
    float* o = out + (size_t)row * OUT_STRIDE + col_off + lane * 4;
    atomicAdd(o + 0, wv * v.x);
    atomicAdd(o + 1, wv * v.y);
    atomicAdd(o + 2, wv * v.z);
    atomicAdd(o + 3, wv * v.w);
}

extern "C" void kernel_launch(void* const* d_in, const int* in_sizes, int n_in,
                              void* d_out, int out_size, void* d_ws, size_t ws_size,
                              hipStream_t stream) {
    const float* x   = (const float*)d_in[0];
    const int*   ei1 = (const int*)d_in[1];
    const float* w1  = (const float*)d_in[2];
    const int*   ei2 = (const int*)d_in[3];
    const float* w2  = (const float*)d_in[4];
    float* out = (float*)d_out;

    const int E1 = in_sizes[1] / 2;   // 800000
    const int E2 = in_sizes[3] / 2;   // 1600000
    const int block = 256;

    // Workspace layout (256-aligned): cnt1 | cnt2 | off1 | off2 | colw1 | colw2
    size_t cnt_b  = align256((size_t)N_NODES * sizeof(int));
    size_t o_cnt1 = 0;
    size_t o_cnt2 = o_cnt1 + cnt_b;
    size_t o_off1 = o_cnt2 + cnt_b;
    size_t o_off2 = o_off1 + cnt_b;
    size_t o_cw1  = o_off2 + cnt_b;
    size_t o_cw2  = o_cw1 + align256((size_t)E1 * sizeof(int2));
    size_t needed = o_cw2 + align256((size_t)E2 * sizeof(int2));

    if (ws_size < needed) {
        // Fallback: round-0 atomic scatter.
        hipMemsetAsync(d_out, 0, (size_t)out_size * sizeof(float), stream);
        long long th1 = (long long)E1 * 32;
        spmm_scatter<<<(int)((th1 + block - 1) / block), block, 0, stream>>>(
            x, ei1, w1, out, E1, 0);
        long long th2 = (long long)E2 * 32;
        spmm_scatter<<<(int)((th2 + block - 1) / block), block, 0, stream>>>(
            x, ei2, w2, out, E2, D);
        return;
    }

    char* ws = (char*)d_ws;
    int*  cnt1  = (int*)(ws + o_cnt1);
    int*  cnt2  = (int*)(ws + o_cnt2);
    int*  off1  = (int*)(ws + o_off1);
    int*  off2  = (int*)(ws + o_off2);
    int2* colw1 = (int2*)(ws + o_cw1);
    int2* colw2 = (int2*)(ws + o_cw2);

    // 1. zero counters (cnt1|cnt2 adjacent)
    hipMemsetAsync(cnt1, 0, 2 * cnt_b, stream);

    // 2. histogram rows
    {
        int total = E1 + E2;
        hist_kernel<<<(total + block - 1) / block, block, 0, stream>>>(
            ei1, E1, ei2, E2, cnt1, cnt2);
    }

    // 3. exclusive scan (both graphs, one block each)
    scan_kernel<<<2, 1024, 0, stream>>>(cnt1, off1, cnt2, off2, N_NODES);

    // 4. scatter edges into buckets (mutates off: off[r] -> end of row r)
    scatter_kernel<<<(E1 + block - 1) / block, block, 0, stream>>>(
        ei1, w1, E1, off1, colw1);
    scatter_kernel<<<(E2 + block - 1) / block, block, 0, stream>>>(
        ei2, w2, E2, off2, colw2);

    // 5. gather SpMM: one wave per row, writes every output element (no memset)
    {
        long long threads = (long long)N_NODES * 64;
        int grid = (int)((threads + block - 1) / block);
        spmm_csr<<<grid, block, 0, stream>>>(x, off1, colw1, off2, colw2, out);
    }
}

// Round 3
// 465.809 us; speedup vs baseline: 8.7901x; 1.3573x over previous
//
#include <hip/hip_runtime.h>

// H2GCNConv: out[:, 0:128]   = segment_sum(w1 * x[col1], row1)
//            out[:, 128:256] = segment_sum(w2 * x[col2], row2)
// N = 50000, d = 128, out stride = 256 floats.
//
// Round 3: (a) gather from bf16-packed x (halves gather bytes; fp32 accum),
//          (b) 3-phase multi-block scan (round-2's 2-block scan was serial),
//          (c) one wave per (row,graph) + 4x unrolled gather for MLP.
// Tiered fallbacks: fp32 CSR (round-2) if ws too small for xb, atomic if tiny.

#define N_NODES 50000
#define D 128
#define OUT_STRIDE 256
#define SCAN_B 256

static inline size_t align256(size_t x) { return (x + 255) & ~(size_t)255; }

// ---------------- CSR build ----------------

__global__ void hist_kernel(const int* __restrict__ ei1, int E1,
                            const int* __restrict__ ei2, int E2,
                            int* cnt1, int* cnt2) {
    int t = blockIdx.x * blockDim.x + threadIdx.x;
    if (t < E1) {
        atomicAdd(&cnt1[ei1[t]], 1);
    } else {
        int u = t - E1;
        if (u < E2) atomicAdd(&cnt2[ei2[u]], 1);
    }
}

// Phase 1: per-block sums. grid = (nb, 2).
__global__ void scan_sums(const int* __restrict__ cnt1, const int* __restrict__ cnt2,
                          int* __restrict__ bsums, int n, int nb) {
    const int* cnt = blockIdx.y ? cnt2 : cnt1;
    int i = blockIdx.x * SCAN_B + threadIdx.x;
    int v = (i < n) ? cnt[i] : 0;
    #pragma unroll
    for (int d = 1; d < 64; d <<= 1) v += __shfl_xor(v, d, 64);
    __shared__ int ws[4];
    if ((threadIdx.x & 63) == 0) ws[threadIdx.x >> 6] = v;
    __syncthreads();
    if (threadIdx.x == 0)
        bsums[blockIdx.y * nb + blockIdx.x] = ws[0] + ws[1] + ws[2] + ws[3];
}

// Phase 2: exclusive scan of block sums in place. grid = 2 blocks (1/segment).
// nb <= 256.
__global__ void scan_bsums(int* bsums, int nb) {
    int* b = bsums + blockIdx.x * nb;
    int i = threadIdx.x;
    int v = (i < nb) ? b[i] : 0;
    int lane = threadIdx.x & 63, wid = threadIdx.x >> 6;
    int s = v;
    #pragma unroll
    for (int d = 1; d < 64; d <<= 1) { int t = __shfl_up(s, d, 64); if (lane >= d) s += t; }
    __shared__ int ws[4];
    if (lane == 63) ws[wid] = s;
    __syncthreads();
    int add = 0;
    #pragma unroll
    for (int k = 0; k < 4; ++k) if (k < wid) add += ws[k];
    s += add;
    if (i < nb) b[i] = s - v;   // exclusive
}

// Phase 3: block-local exclusive scan + block base -> off. grid = (nb, 2).
__global__ void scan_apply(const int* __restrict__ cnt1, int* __restrict__ off1,
                           const int* __restrict__ cnt2, int* __restrict__ off2,
                           const int* __restrict__ bsums, int n, int nb) {
    const int* cnt = blockIdx.y ? cnt2 : cnt1;
    int* off       = blockIdx.y ? off2 : off1;
    int base = bsums[blockIdx.y * nb + blockIdx.x];
    int i = blockIdx.x * SCAN_B + threadIdx.x;
    int v = (i < n) ? cnt[i] : 0;
    int lane = threadIdx.x & 63, wid = threadIdx.x >> 6;
    int s = v;
    #pragma unroll
    for (int d = 1; d < 64; d <<= 1) { int t = __shfl_up(s, d, 64); if (lane >= d) s += t; }
    __shared__ int ws[4];
    if (lane == 63) ws[wid] = s;
    __syncthreads();
    int add = 0;
    #pragma unroll
    for (int k = 0; k < 4; ++k) if (k < wid) add += ws[k];
    s += add;
    if (i < n) off[i] = base + s - v;   // exclusive
}

// Scatter edges into row buckets. atomicAdd on off[] itself: afterwards
// off[r] = end of row r; start of row r is off[r-1] (0 for r=0).
__global__ void scatter_kernel(const int* __restrict__ ei,
                               const float* __restrict__ w, int E,
                               int* off, int2* colw) {
    int t = blockIdx.x * blockDim.x + threadIdx.x;
    if (t >= E) return;
    int row = ei[t];
    int pos = atomicAdd(&off[row], 1);
    colw[pos] = make_int2(ei[E + t], __float_as_int(w[t]));
}

// x [N,128] f32 -> xb [N,64] packed bf16x2 (round-to-nearest).
__global__ void cvt_bf16(const float* __restrict__ x, unsigned* __restrict__ xb, int n2) {
    int i = blockIdx.x * blockDim.x + threadIdx.x;
    if (i >= n2) return;
    float2 v = ((const float2*)x)[i];
    unsigned a = __float_as_uint(v.x);
    unsigned b = __float_as_uint(v.y);
    a = (a + 0x7fffu + ((a >> 16) & 1u)) >> 16;
    b = (b + 0x7fffu + ((b >> 16) & 1u)) >> 16;
    xb[i] = a | (b << 16);
}

// ---------------- SpMM: one wave per (row, graph), bf16 gather ----------------

__device__ __forceinline__ void fma_pair(unsigned p, float w, float& ax, float& ay) {
    ax += w * __int_as_float((int)(p << 16));
    ay += w * __int_as_float((int)(p & 0xffff0000u));
}

__global__ void __launch_bounds__(256) spmm_bf16(
        const unsigned* __restrict__ xb,  // [N,64] bf16x2
        const int* __restrict__ off1, const int2* __restrict__ colw1,
        const int* __restrict__ off2, const int2* __restrict__ colw2,
        float* __restrict__ out) {
    int seg  = (int)((blockIdx.x * blockDim.x + threadIdx.x) >> 6);
    int lane = threadIdx.x & 63;
    if (seg >= 2 * N_NODES) return;
    int g    = (seg >= N_NODES) ? 1 : 0;
    int row  = g ? seg - N_NODES : seg;
    const int*  off  = g ? off2  : off1;
    const int2* colw = g ? colw2 : colw1;
    int s = row ? off[row - 1] : 0;
    int e = off[row];

    float ax = 0.f, ay = 0.f;
    int j = s;
    for (; j + 4 <= e; j += 4) {
        int2 c0 = colw[j];
        int2 c1 = colw[j + 1];
        int2 c2 = colw[j + 2];
        int2 c3 = colw[j + 3];
        unsigned p0 = xb[(size_t)c0.x * 64 + lane];
        unsigned p1 = xb[(size_t)c1.x * 64 + lane];
        unsigned p2 = xb[(size_t)c2.x * 64 + lane];
        unsigned p3 = xb[(size_t)c3.x * 64 + lane];
        fma_pair(p0, __int_as_float(c0.y), ax, ay);
        fma_pair(p1, __int_as_float(c1.y), ax, ay);
        fma_pair(p2, __int_as_float(c2.y), ax, ay);
        fma_pair(p3, __int_as_float(c3.y), ax, ay);
    }
    for (; j < e; ++j) {
        int2 c = colw[j];
        unsigned p = xb[(size_t)c.x * 64 + lane];
        fma_pair(p, __int_as_float(c.y), ax, ay);
    }
    float2* o = (float2*)(out + (size_t)row * OUT_STRIDE + g * D);
    o[lane] = make_float2(ax, ay);
}

// ---------------- fp32 CSR SpMM (tier-2 fallback, round-2 kernel) ----------------

__global__ void __launch_bounds__(256) spmm_csr(const float* __restrict__ x,
                                                const int* __restrict__ off1,
                                                const int2* __restrict__ colw1,
                                                const int* __restrict__ off2,
                                                const int2* __restrict__ colw2,
                                                float* __restrict__ out) {
    int row  = (int)((blockIdx.x * blockDim.x + threadIdx.x) >> 6);
    int lane = threadIdx.x & 63;
    if (row >= N_NODES) return;
    float2* o = (float2*)(out + (size_t)row * OUT_STRIDE);
    {
        int s = row ? off1[row - 1] : 0;
        int e = off1[row];
        float2 acc = make_float2(0.f, 0.f);
        for (int j = s; j < e; ++j) {
            int2 cw = colw1[j];
            float wv = __int_as_float(cw.y);
            float2 v = ((const float2*)(x + (size_t)cw.x * D))[lane];
            acc.x += wv * v.x;
            acc.y += wv * v.y;
        }
        o[lane] = acc;
    }
    {
        int s = row ? off2[row - 1] : 0;
        int e = off2[row];
        float2 acc = make_float2(0.f, 0.f);
        for (int j = s; j < e; ++j) {
            int2 cw = colw2[j];
            float wv = __int_as_float(cw.y);
            float2 v = ((const float2*)(x + (size_t)cw.x * D))[lane];
            acc.x += wv * v.x;
            acc.y += wv * v.y;
        }
        o[64 + lane] = acc;
    }
}

// ---------------- atomic scatter (tier-3 fallback, round-0 kernel) ----------------

__global__ void spmm_scatter(const float* __restrict__ x,
                             const int* __restrict__ ei,
                             const float* __restrict__ w,
                             float* __restrict__ out,
                             int E, int col_off) {
    long long gid = (long long)blockIdx.x * blockDim.x + threadIdx.x;
    int e    = (int)(gid >> 5);
    int lane = (int)(gid & 31);
    if (e >= E) return;
    int row  = ei[e];
    int col  = ei[E + e];
    float wv = w[e];
    const float4* xv = (const float4*)(x + (size_t)col * D);
    float4 v = xv[lane];
    float* o = out + (size_t)row * OUT_STRIDE + col_off + lane * 4;
    atomicAdd(o + 0, wv * v.x);
    atomicAdd(o + 1, wv * v.y);
    atomicAdd(o + 2, wv * v.z);
    atomicAdd(o + 3, wv * v.w);
}

extern "C" void kernel_launch(void* const* d_in, const int* in_sizes, int n_in,
                              void* d_out, int out_size, void* d_ws, size_t ws_size,
                              hipStream_t stream) {
    const float* x   = (const float*)d_in[0];
    const int*   ei1 = (const int*)d_in[1];
    const float* w1  = (const float*)d_in[2];
    const int*   ei2 = (const int*)d_in[3];
    const float* w2  = (const float*)d_in[4];
    float* out = (float*)d_out;

    const int E1 = in_sizes[1] / 2;   // 800000
    const int E2 = in_sizes[3] / 2;   // 1600000
    const int block = 256;
    const int nb = (N_NODES + SCAN_B - 1) / SCAN_B;   // 196

    // Workspace layout: cnt1 | cnt2 | off1 | off2 | bsums | colw1 | colw2 | xb
    size_t cnt_b   = align256((size_t)N_NODES * sizeof(int));
    size_t o_cnt1  = 0;
    size_t o_cnt2  = o_cnt1 + cnt_b;
    size_t o_off1  = o_cnt2 + cnt_b;
    size_t o_off2  = o_off1 + cnt_b;
    size_t o_bsum  = o_off2 + cnt_b;
    size_t o_cw1   = o_bsum + align256((size_t)2 * nb * sizeof(int));
    size_t o_cw2   = o_cw1 + align256((size_t)E1 * sizeof(int2));
    size_t o_xb    = o_cw2 + align256((size_t)E2 * sizeof(int2));
    size_t need_csr  = o_xb;
    size_t need_bf16 = o_xb + align256((size_t)N_NODES * 64 * sizeof(unsigned));

    if (ws_size < need_csr) {
        // Tier 3: atomic scatter.
        hipMemsetAsync(d_out, 0, (size_t)out_size * sizeof(float), stream);
        long long th1 = (long long)E1 * 32;
        spmm_scatter<<<(int)((th1 + block - 1) / block), block, 0, stream>>>(
            x, ei1, w1, out, E1, 0);
        long long th2 = (long long)E2 * 32;
        spmm_scatter<<<(int)((th2 + block - 1) / block), block, 0, stream>>>(
            x, ei2, w2, out, E2, D);
        return;
    }

    char* ws = (char*)d_ws;
    int*      cnt1  = (int*)(ws + o_cnt1);
    int*      cnt2  = (int*)(ws + o_cnt2);
    int*      off1  = (int*)(ws + o_off1);
    int*      off2  = (int*)(ws + o_off2);
    int*      bsums = (int*)(ws + o_bsum);
    int2*     colw1 = (int2*)(ws + o_cw1);
    int2*     colw2 = (int2*)(ws + o_cw2);
    unsigned* xb    = (unsigned*)(ws + o_xb);
    bool use_bf16 = (ws_size >= need_bf16);

    // 1. zero counters (cnt1|cnt2 adjacent)
    hipMemsetAsync(cnt1, 0, 2 * cnt_b, stream);

    // 2. histogram rows
    {
        int total = E1 + E2;
        hist_kernel<<<(total + block - 1) / block, block, 0, stream>>>(
            ei1, E1, ei2, E2, cnt1, cnt2);
    }

    // 3. 3-phase exclusive scan (both graphs)
    {
        dim3 g1(nb, 2);
        scan_sums<<<g1, SCAN_B, 0, stream>>>(cnt1, cnt2, bsums, N_NODES, nb);
        scan_bsums<<<2, SCAN_B, 0, stream>>>(bsums, nb);
        scan_apply<<<g1, SCAN_B, 0, stream>>>(cnt1, off1, cnt2, off2, bsums,
                                              N_NODES, nb);
    }

    // 4. scatter edges into buckets (mutates off: off[r] -> end of row r)
    scatter_kernel<<<(E1 + block - 1) / block, block, 0, stream>>>(
        ei1, w1, E1, off1, colw1);
    scatter_kernel<<<(E2 + block - 1) / block, block, 0, stream>>>(
        ei2, w2, E2, off2, colw2);

    if (use_bf16) {
        // 5a. pack x to bf16x2 (independent of steps 2-4)
        int n2 = N_NODES * 64;
        cvt_bf16<<<(n2 + block - 1) / block, block, 0, stream>>>(x, xb, n2);
        // 6a. gather SpMM, one wave per (row, graph)
        long long threads = (long long)2 * N_NODES * 64;
        int grid = (int)((threads + block - 1) / block);
        spmm_bf16<<<grid, block, 0, stream>>>(xb, off1, colw1, off2, colw2, out);
    } else {
        // 5b. fp32 gather SpMM (round-2)
        long long threads = (long long)N_NODES * 64;
        int grid = (int)((threads + block - 1) / block);
        spmm_csr<<<grid, block, 0, stream>>>(x, off1, colw1, off2, colw2, out);
    }
}